// Round 3
// baseline (510.502 us; speedup 1.0000x reference)
//
#include <hip/hip_runtime.h>

typedef __bf16 bf16;
typedef __attribute__((ext_vector_type(4))) __bf16 bf16x4;
typedef __attribute__((ext_vector_type(8))) __bf16 bf16x8;
typedef __attribute__((ext_vector_type(4))) float f32x4;

#define LDS16(gp, lp)                                                          \
  __builtin_amdgcn_global_load_lds(                                            \
      (const __attribute__((address_space(1))) void*)(gp),                     \
      (__attribute__((address_space(3))) void*)(lp), 16, 0, 0)

// ---------------------------------------------------------------------------
// f32 -> bf16 cast, 8 elems/thread
__global__ __launch_bounds__(256) void cast_bf16_kernel(const float* __restrict__ src,
                                                        bf16* __restrict__ dst, int n) {
  int i = (blockIdx.x * 256 + threadIdx.x) * 8;
  if (i < n) {
    float4 a = *(const float4*)(src + i);
    float4 b = *(const float4*)(src + i + 4);
    bf16x8 v;
    v[0] = (bf16)a.x; v[1] = (bf16)a.y; v[2] = (bf16)a.z; v[3] = (bf16)a.w;
    v[4] = (bf16)b.x; v[5] = (bf16)b.y; v[6] = (bf16)b.z; v[7] = (bf16)b.w;
    *(bf16x8*)(dst + i) = v;
  }
}

__global__ __launch_bounds__(256) void zero_kernel(float* p, int n) {
  int i = blockIdx.x * 256 + threadIdx.x;
  if (i < n) p[i] = 0.f;
}

// ---------------------------------------------------------------------------
// 128x128-tile bf16 MFMA GEMM, C = A(MxK) * B(NxK)^T with per-sample B.
// Grid: (M-blocks-within-sample, N-blocks, sample). Chunk-swizzled LDS.
// MODE 0: gate  -> relu(C + bias[col]) column-sums atomically into fout[b*512+col]
// MODE 1: FFN1  -> h = relu(C + bias[b,col]) bf16, coalesced via LDS transpose
template <int MODE, int KTILES>
__global__ __launch_bounds__(256) void gemm_bt(const bf16* __restrict__ A,
                                               const bf16* __restrict__ B0, long bstride,
                                               const float* __restrict__ bias, long biasStride,
                                               float* __restrict__ fout,
                                               bf16* __restrict__ hout) {
  constexpr int K = KTILES * 64;
  __shared__ bf16 smem[2 * 128 * 64];
  bf16* As = smem;
  bf16* Bs = smem + 8192;
  const int tid = threadIdx.x;
  const int lane = tid & 63, wv = tid >> 6;
  const int wm = wv >> 1, wn = wv & 1;
  const int lr = lane & 15, q = lane >> 4;
  const int b = blockIdx.z;
  const long blockM = (long)b * 4096 + (long)blockIdx.x * 128;
  const int blockN = blockIdx.y * 128;
  const bf16* Bp = B0 + (long)b * bstride;

  f32x4 acc[4][4] = {};

  const bf16* Ab = A + blockM * K;
  const bf16* Bb = Bp + (long)blockN * K;
  const int srow = lane >> 3;                        // 0..7
  const int scol = ((lane & 7) ^ srow) * 8;          // swizzled source column

  for (int it = 0; it < KTILES; ++it) {
    const int k0 = it * 64;
#pragma unroll
    for (int c = 0; c < 4; ++c) {
      int n = wv * 4 + c;
      int row = n * 8 + srow;
      LDS16(Ab + (long)row * K + k0 + scol, &As[n * 512]);
      LDS16(Bb + (long)row * K + k0 + scol, &Bs[n * 512]);
    }
    __syncthreads();
#pragma unroll
    for (int ks = 0; ks < 2; ++ks) {
      const int c0 = ks * 4 + q;
      const int sw = lane & 7;
      bf16x8 af[4], bfr[4];
#pragma unroll
      for (int i = 0; i < 4; ++i)
        af[i] = *(const bf16x8*)&As[(wm * 64 + i * 16 + lr) * 64 + ((c0 ^ sw) * 8)];
#pragma unroll
      for (int j = 0; j < 4; ++j)
        bfr[j] = *(const bf16x8*)&Bs[(wn * 64 + j * 16 + lr) * 64 + ((c0 ^ sw) * 8)];
#pragma unroll
      for (int i = 0; i < 4; ++i)
#pragma unroll
        for (int j = 0; j < 4; ++j)
          acc[i][j] = __builtin_amdgcn_mfma_f32_16x16x32_bf16(af[i], bfr[j], acc[i][j], 0, 0, 0);
    }
    __syncthreads();
  }

  // Epilogue. C/D layout: col = lane&15, row = (lane>>4)*4 + reg  [m89/m91]
  if (MODE == 0) {
#pragma unroll
    for (int j = 0; j < 4; ++j) {
      const int gc = blockN + wn * 64 + j * 16 + lr;
      const float bv = bias[gc];
      float s = 0.f;
#pragma unroll
      for (int i = 0; i < 4; ++i)
#pragma unroll
        for (int r = 0; r < 4; ++r) {
          float v = acc[i][j][r] + bv;
          s += v > 0.f ? v : 0.f;
        }
      s += __shfl_xor(s, 16);
      s += __shfl_xor(s, 32);
      if (q == 0) atomicAdd(&fout[b * 512 + gc], s);
    }
  } else {
    // relu -> bf16 tile in LDS (row-major 128x128), then coalesced 16B stores
#pragma unroll
    for (int j = 0; j < 4; ++j) {
      const int gc = wn * 64 + j * 16 + lr;
      const float bv = bias[(long)b * biasStride + blockN + gc];
#pragma unroll
      for (int i = 0; i < 4; ++i)
#pragma unroll
        for (int r = 0; r < 4; ++r) {
          const int lrow = wm * 64 + i * 16 + q * 4 + r;
          float v = acc[i][j][r] + bv;
          smem[lrow * 128 + gc] = (bf16)(v > 0.f ? v : 0.f);
        }
    }
    __syncthreads();
#pragma unroll
    for (int p = 0; p < 8; ++p) {
      const int row = p * 16 + (tid >> 4);
      const int col = (tid & 15) * 8;
      *(bf16x8*)&hout[(blockM + row) * 2048 + blockN + col] =
          *(const bf16x8*)&smem[row * 128 + col];
    }
  }
}

// ---------------------------------------------------------------------------
// FFN2 + residual + layernorm, fused. Tile 128(M) x 512(N=D full row), 8 waves.
// A (h rows) streamed directly from global; B (W2m) LDS16-staged 512x64 (64 KB,
// XOR-swizzled). After the K-loop the LDS is reused for LN partial sums.
__global__ __launch_bounds__(512) void ffn2_ln_kernel(
    const bf16* __restrict__ h, const bf16* __restrict__ W2m,
    const float* __restrict__ b2m, const float* __restrict__ xres,
    const float* __restrict__ lng, const float* __restrict__ lnb,
    float* __restrict__ out) {
  __shared__ bf16 Bs[512 * 64];  // 64 KB; reused as LN partial buffer
  const int tid = threadIdx.x;
  const int lane = tid & 63, wv = tid >> 6;  // 8 waves
  const int wm = wv >> 2, wn = wv & 3;       // 2 (M) x 4 (N)
  const int lr = lane & 15, q = lane >> 4;
  const int b = blockIdx.z;
  const long blockM = (long)b * 4096 + (long)blockIdx.x * 128;
  const bf16* Bb = W2m + (long)b * 1048576;  // [512][2048]
  const bf16* Ab = h + blockM * 2048;

  f32x4 acc[4][8] = {};
  const int srow = lane >> 3;
  const int scol = ((lane & 7) ^ srow) * 8;

  for (int it = 0; it < 32; ++it) {
    const int k0 = it * 64;
    // A-fragments direct from global (16 rows x 64B per instr, L1/L2-backed)
    bf16x8 af[4][2];
#pragma unroll
    for (int i = 0; i < 4; ++i)
#pragma unroll
      for (int kk = 0; kk < 2; ++kk)
        af[i][kk] = *(const bf16x8*)(Ab + (long)(wm * 64 + i * 16 + lr) * 2048 +
                                     k0 + kk * 32 + q * 8);
    // stage W2m tile 512x64 (8 LDS16 per lane)
#pragma unroll
    for (int c = 0; c < 8; ++c) {
      int grp = wv * 8 + c;  // 64 groups of 8 rows
      int row = grp * 8 + srow;
      LDS16(Bb + (long)row * 2048 + k0 + scol, &Bs[grp * 512]);
    }
    __syncthreads();
#pragma unroll
    for (int kk = 0; kk < 2; ++kk) {
      bf16x8 bfr[8];
#pragma unroll
      for (int j = 0; j < 8; ++j) {
        int n = wn * 128 + j * 16 + lr;
        bfr[j] = *(const bf16x8*)&Bs[n * 64 + (((kk * 4 + q) ^ (n & 7)) * 8)];
      }
#pragma unroll
      for (int i = 0; i < 4; ++i)
#pragma unroll
        for (int j = 0; j < 8; ++j)
          acc[i][j] = __builtin_amdgcn_mfma_f32_16x16x32_bf16(af[i][kk], bfr[j], acc[i][j], 0, 0, 0);
    }
    __syncthreads();
  }

  // ---- epilogue: v = acc + b2m + x; per-row LN across 4 n-waves via LDS ----
  float bv[8], lg[8], lb[8];
  int gc[8];
#pragma unroll
  for (int j = 0; j < 8; ++j) {
    gc[j] = wn * 128 + j * 16 + lr;
    bv[j] = b2m[b * 512 + gc[j]];
    lg[j] = lng[gc[j]];
    lb[j] = lnb[gc[j]];
  }
  float p1[4][4], p2[4][4];
#pragma unroll
  for (int i = 0; i < 4; ++i)
#pragma unroll
    for (int r = 0; r < 4; ++r) {
      const long gr = blockM + wm * 64 + i * 16 + q * 4 + r;
      float s1 = 0.f, s2 = 0.f;
#pragma unroll
      for (int j = 0; j < 8; ++j) {
        float v = acc[i][j][r] + bv[j] + xres[gr * 512 + gc[j]];
        acc[i][j][r] = v;
        s1 += v;
        s2 += v * v;
      }
      s1 += __shfl_xor(s1, 1); s2 += __shfl_xor(s2, 1);
      s1 += __shfl_xor(s1, 2); s2 += __shfl_xor(s2, 2);
      s1 += __shfl_xor(s1, 4); s2 += __shfl_xor(s2, 4);
      s1 += __shfl_xor(s1, 8); s2 += __shfl_xor(s2, 8);
      p1[i][r] = s1;
      p2[i][r] = s2;
    }
  float2* P = (float2*)Bs;  // [128 rows][4 wn]
  if (lr == 0) {
#pragma unroll
    for (int i = 0; i < 4; ++i)
#pragma unroll
      for (int r = 0; r < 4; ++r)
        P[(wm * 64 + i * 16 + q * 4 + r) * 4 + wn] = make_float2(p1[i][r], p2[i][r]);
  }
  __syncthreads();
#pragma unroll
  for (int i = 0; i < 4; ++i)
#pragma unroll
    for (int r = 0; r < 4; ++r) {
      const int row = wm * 64 + i * 16 + q * 4 + r;
      float2 a0 = P[row * 4 + 0], a1 = P[row * 4 + 1];
      float2 a2 = P[row * 4 + 2], a3 = P[row * 4 + 3];
      const float s1 = a0.x + a1.x + a2.x + a3.x;
      const float s2 = a0.y + a1.y + a2.y + a3.y;
      const float mean = s1 * (1.f / 512.f);
      const float var = s2 * (1.f / 512.f) - mean * mean;
      const float rstd = rsqrtf(var + 1e-5f);
      const long gr = blockM + row;
#pragma unroll
      for (int j = 0; j < 8; ++j)
        out[gr * 512 + gc[j]] = (acc[i][j][r] - mean) * rstd * lg[j] + lb[j];
    }
}

// ---------------------------------------------------------------------------
// Tiny per-launch kernel: g[b,e], merged ln params, merged biases.
__global__ __launch_bounds__(512) void small_kernel(
    const float* __restrict__ ghsum, const float* __restrict__ g2w,
    const float* __restrict__ g2b, const float* __restrict__ lngI,
    const float* __restrict__ lnbI, const float* __restrict__ tvlg,
    const float* __restrict__ tvlb, const float* __restrict__ b1,
    const float* __restrict__ tvb1, const float* __restrict__ b2,
    const float* __restrict__ tvb2, float* __restrict__ g, float* __restrict__ lng,
    float* __restrict__ lnb, float* __restrict__ b1m, float* __restrict__ b2m) {
  __shared__ float gs[64];
  const int t = threadIdx.x;
  if (t < 64) {
    const int b = t >> 3, e = t & 7;
    float s = 0.f;
    for (int h = 0; h < 512; ++h) s += ghsum[b * 512 + h] * g2w[e * 512 + h];
    float gv = s * (1.f / 4096.f) + g2b[e];
    gs[t] = gv;
    g[t] = gv;
  }
  __syncthreads();
  if (t < 512) {
    float lg = lngI[t], lb = lnbI[t], sg = 0.f, sb = 0.f;
    for (int e = 0; e < 8; ++e) { sg += tvlg[e * 512 + t]; sb += tvlb[e * 512 + t]; }
    lng[t] = lg + 0.03f * (sg - 8.f * lg);
    lnb[t] = lb + 0.03f * (sb - 8.f * lb);
  }
  for (int i = t; i < 8 * 2048; i += 512) {
    const int b = i >> 11, f = i & 2047;
    float s = b1[f];
    for (int e = 0; e < 8; ++e) s += gs[b * 8 + e] * tvb1[e * 2048 + f];
    b1m[i] = s;
  }
  for (int i = t; i < 8 * 512; i += 512) {
    const int b = i >> 9, d = i & 511;
    float s = b2[d];
    for (int e = 0; e < 8; ++e) s += gs[b * 8 + e] * tvb2[e * 512 + d];
    b2m[i] = s;
  }
}

// ---------------------------------------------------------------------------
// Merge base + rank-8 task-vector combo into per-sample bf16 weights.
// Vectorized x4: each thread handles 4 consecutive elements, 8 samples.
__global__ __launch_bounds__(256) void merge_kernel(
    const float* __restrict__ W1, const float* __restrict__ tvW1,
    const float* __restrict__ W2, const float* __restrict__ tvW2,
    const float* __restrict__ g, bf16* __restrict__ W1m, bf16* __restrict__ W2m) {
  int idx = (blockIdx.x * 256 + threadIdx.x) * 4;
  const float* Wp;
  const float* tvp;
  bf16* outp;
  if (idx < 1048576) {
    Wp = W1; tvp = tvW1; outp = W1m;
  } else {
    idx -= 1048576;
    Wp = W2; tvp = tvW2; outp = W2m;
  }
  float4 w = *(const float4*)(Wp + idx);
  float4 tv[8];
#pragma unroll
  for (int e = 0; e < 8; ++e) tv[e] = *(const float4*)(tvp + (long)e * 1048576 + idx);
#pragma unroll
  for (int b = 0; b < 8; ++b) {
    float4 s = w;
#pragma unroll
    for (int e = 0; e < 8; ++e) {
      const float ge = g[b * 8 + e];
      s.x += ge * tv[e].x; s.y += ge * tv[e].y;
      s.z += ge * tv[e].z; s.w += ge * tv[e].w;
    }
    bf16x4 o;
    o[0] = (bf16)s.x; o[1] = (bf16)s.y; o[2] = (bf16)s.z; o[3] = (bf16)s.w;
    *(bf16x4*)(outp + (long)b * 1048576 + idx) = o;
  }
}

// ---------------------------------------------------------------------------
extern "C" void kernel_launch(void* const* d_in, const int* in_sizes, int n_in,
                              void* d_out, int out_size, void* d_ws, size_t ws_size,
                              hipStream_t stream) {
  const float* x    = (const float*)d_in[0];
  const float* g1w  = (const float*)d_in[1];
  const float* g1b  = (const float*)d_in[2];
  const float* g2w  = (const float*)d_in[3];
  const float* g2b  = (const float*)d_in[4];
  const float* W1   = (const float*)d_in[5];
  const float* b1   = (const float*)d_in[6];
  const float* W2   = (const float*)d_in[7];
  const float* b2   = (const float*)d_in[8];
  const float* lngI = (const float*)d_in[9];
  const float* lnbI = (const float*)d_in[10];
  const float* tvW1 = (const float*)d_in[11];
  const float* tvb1 = (const float*)d_in[12];
  const float* tvW2 = (const float*)d_in[13];
  const float* tvb2 = (const float*)d_in[14];
  const float* tvlg = (const float*)d_in[15];
  const float* tvlb = (const float*)d_in[16];
  float* out = (float*)d_out;

  char* w = (char*)d_ws;
  bf16*  x_bf   = (bf16*)(w);                   // 33,554,432 B
  bf16*  g1w_bf = (bf16*)(w + 33554432);        //    524,288 B
  bf16*  W1m    = (bf16*)(w + 34078720);        // 16,777,216 B
  bf16*  W2m    = (bf16*)(w + 50855936);        // 16,777,216 B
  bf16*  h      = (bf16*)(w + 67633152);        // 134,217,728 B
  float* ghsum  = (float*)(w + 201850880);      //     16,384 B
  float* g      = (float*)(w + 201867264);      //        256 B
  float* b1m    = (float*)(w + 201867520);      //     65,536 B
  float* b2m    = (float*)(w + 201933056);      //     16,384 B
  float* lng    = (float*)(w + 201949440);      //      2,048 B
  float* lnb    = (float*)(w + 201951488);      //      2,048 B

  // Stage 0: casts + zero gate accumulator
  cast_bf16_kernel<<<8192, 256, 0, stream>>>(x, x_bf, 16777216);
  cast_bf16_kernel<<<128, 256, 0, stream>>>(g1w, g1w_bf, 262144);
  zero_kernel<<<16, 256, 0, stream>>>(ghsum, 4096);
  // Stage 1: gate GEMM + relu column-sum   (per sample: M=4096, N=512, K=512)
  gemm_bt<0, 8><<<dim3(32, 4, 8), 256, 0, stream>>>(x_bf, g1w_bf, 0, g1b, 0,
                                                    ghsum, nullptr);
  // Stage 2: g, merged ln params, merged biases
  small_kernel<<<1, 512, 0, stream>>>(ghsum, g2w, g2b, lngI, lnbI, tvlg, tvlb,
                                      b1, tvb1, b2, tvb2, g, lng, lnb, b1m, b2m);
  // Stage 3: per-sample weight merge -> bf16 (x4 vectorized)
  merge_kernel<<<2048, 256, 0, stream>>>(W1, tvW1, W2, tvW2, g, W1m, W2m);
  // Stage 4: h = relu(x @ W1m^T + b1m)     (per sample: M=4096, N=2048, K=512)
  gemm_bt<1, 8><<<dim3(32, 16, 8), 256, 0, stream>>>(x_bf, W1m, 1048576, b1m, 2048,
                                                     nullptr, h);
  // Stage 5: out = LN(h @ W2m^T + b2m + x) fused (per sample: M=4096, N=512, K=2048)
  ffn2_ln_kernel<<<dim3(32, 1, 8), 512, 0, stream>>>(h, W2m, b2m, x, lng, lnb, out);
}

// Round 4
// 481.424 us; speedup vs baseline: 1.0604x; 1.0604x over previous
//
#include <hip/hip_runtime.h>

typedef __bf16 bf16;
typedef __attribute__((ext_vector_type(4))) __bf16 bf16x4;
typedef __attribute__((ext_vector_type(8))) __bf16 bf16x8;
typedef __attribute__((ext_vector_type(4))) float f32x4;

#define LDS16(gp, lp)                                                          \
  __builtin_amdgcn_global_load_lds(                                            \
      (const __attribute__((address_space(1))) void*)(gp),                     \
      (__attribute__((address_space(3))) void*)(lp), 16, 0, 0)

// ---------------------------------------------------------------------------
// Fused prologue: cast x -> bf16 (blocks 0..8191), cast g1w -> bf16
// (blocks 8192..8319), zero ghsum (block 8320).
__global__ __launch_bounds__(256) void prep_kernel(const float* __restrict__ x,
                                                   const float* __restrict__ g1w,
                                                   bf16* __restrict__ x_bf,
                                                   bf16* __restrict__ g1w_bf,
                                                   float* __restrict__ ghsum) {
  const int bid = blockIdx.x;
  if (bid < 8320) {
    const float* src = bid < 8192 ? x : g1w;
    bf16* dst = bid < 8192 ? x_bf : g1w_bf;
    const int base = bid < 8192 ? bid : bid - 8192;
    int i = (base * 256 + threadIdx.x) * 8;
    float4 a = *(const float4*)(src + i);
    float4 b = *(const float4*)(src + i + 4);
    bf16x8 v;
    v[0] = (bf16)a.x; v[1] = (bf16)a.y; v[2] = (bf16)a.z; v[3] = (bf16)a.w;
    v[4] = (bf16)b.x; v[5] = (bf16)b.y; v[6] = (bf16)b.z; v[7] = (bf16)b.w;
    *(bf16x8*)(dst + i) = v;
  } else {
    float4 z = make_float4(0.f, 0.f, 0.f, 0.f);
    float* p = ghsum + threadIdx.x * 16;
#pragma unroll
    for (int k = 0; k < 4; ++k) *(float4*)(p + k * 4) = z;
  }
}

// ---------------------------------------------------------------------------
// 128x128-tile bf16 MFMA GEMM, C = A(MxK) * B(NxK)^T with per-sample B.
// Grid: (M-blocks-within-sample, N-blocks, sample). XOR-chunk-swizzled LDS
// (swizzle compensated in the per-lane GLOBAL source address; LDS dest of
// global_load_lds stays wave-uniform base + lane*16).
// MODE 0: gate  -> relu(C + bias[col]) column-sums atomically into fout[b*512+col]
// MODE 1: FFN1  -> h = relu(C + bias[b,col]) bf16, coalesced via LDS transpose
// MODE 2: FFN2  -> out = C + bias[b,col] + resid[row,col] stored f32
template <int MODE, int KTILES>
__global__ __launch_bounds__(256) void gemm_bt(const bf16* __restrict__ A,
                                               const bf16* __restrict__ B0, long bstride,
                                               const float* __restrict__ bias, long biasStride,
                                               const float* __restrict__ resid,
                                               float* __restrict__ fout,
                                               bf16* __restrict__ hout) {
  constexpr int K = KTILES * 64;
  __shared__ bf16 smem[2 * 128 * 64];
  bf16* As = smem;
  bf16* Bs = smem + 8192;
  const int tid = threadIdx.x;
  const int lane = tid & 63, wv = tid >> 6;
  const int wm = wv >> 1, wn = wv & 1;
  const int lr = lane & 15, q = lane >> 4;
  const int b = blockIdx.z;
  const long blockM = (long)b * 4096 + (long)blockIdx.x * 128;
  const int blockN = blockIdx.y * 128;
  const bf16* Bp = B0 + (long)b * bstride;

  f32x4 acc[4][4] = {};

  const bf16* Ab = A + blockM * K;
  const bf16* Bb = Bp + (long)blockN * K;
  const int srow = lane >> 3;                        // 0..7
  const int scol = ((lane & 7) ^ srow) * 8;          // swizzled source column

  for (int it = 0; it < KTILES; ++it) {
    const int k0 = it * 64;
#pragma unroll
    for (int c = 0; c < 4; ++c) {
      int n = wv * 4 + c;
      int row = n * 8 + srow;
      LDS16(Ab + (long)row * K + k0 + scol, &As[n * 512]);
      LDS16(Bb + (long)row * K + k0 + scol, &Bs[n * 512]);
    }
    __syncthreads();
#pragma unroll
    for (int ks = 0; ks < 2; ++ks) {
      const int c0 = ks * 4 + q;
      const int sw = lane & 7;
      bf16x8 af[4], bfr[4];
#pragma unroll
      for (int i = 0; i < 4; ++i)
        af[i] = *(const bf16x8*)&As[(wm * 64 + i * 16 + lr) * 64 + ((c0 ^ sw) * 8)];
#pragma unroll
      for (int j = 0; j < 4; ++j)
        bfr[j] = *(const bf16x8*)&Bs[(wn * 64 + j * 16 + lr) * 64 + ((c0 ^ sw) * 8)];
#pragma unroll
      for (int i = 0; i < 4; ++i)
#pragma unroll
        for (int j = 0; j < 4; ++j)
          acc[i][j] = __builtin_amdgcn_mfma_f32_16x16x32_bf16(af[i], bfr[j], acc[i][j], 0, 0, 0);
    }
    __syncthreads();
  }

  // Epilogue. C/D layout: col = lane&15, row = (lane>>4)*4 + reg  [m89/m91]
  if (MODE == 0) {
#pragma unroll
    for (int j = 0; j < 4; ++j) {
      const int gc = blockN + wn * 64 + j * 16 + lr;
      const float bv = bias[gc];
      float s = 0.f;
#pragma unroll
      for (int i = 0; i < 4; ++i)
#pragma unroll
        for (int r = 0; r < 4; ++r) {
          float v = acc[i][j][r] + bv;
          s += v > 0.f ? v : 0.f;
        }
      s += __shfl_xor(s, 16);
      s += __shfl_xor(s, 32);
      if (q == 0) atomicAdd(&fout[b * 512 + gc], s);
    }
  } else if (MODE == 1) {
    // relu -> bf16 tile in LDS (row-major 128x128), then coalesced 16B stores
#pragma unroll
    for (int j = 0; j < 4; ++j) {
      const int gc = wn * 64 + j * 16 + lr;
      const float bv = bias[(long)b * biasStride + blockN + gc];
#pragma unroll
      for (int i = 0; i < 4; ++i)
#pragma unroll
        for (int r = 0; r < 4; ++r) {
          const int lrow = wm * 64 + i * 16 + q * 4 + r;
          float v = acc[i][j][r] + bv;
          smem[lrow * 128 + gc] = (bf16)(v > 0.f ? v : 0.f);
        }
    }
    __syncthreads();
#pragma unroll
    for (int p = 0; p < 8; ++p) {
      const int row = p * 16 + (tid >> 4);
      const int col = (tid & 15) * 8;
      *(bf16x8*)&hout[(blockM + row) * 2048 + blockN + col] =
          *(const bf16x8*)&smem[row * 128 + col];
    }
  } else {
#pragma unroll
    for (int j = 0; j < 4; ++j) {
      const int gc = blockN + wn * 64 + j * 16 + lr;
      const float bv = bias[(long)b * biasStride + gc];
#pragma unroll
      for (int i = 0; i < 4; ++i)
#pragma unroll
        for (int r = 0; r < 4; ++r) {
          const long gr = blockM + wm * 64 + i * 16 + q * 4 + r;
          fout[gr * 512 + gc] = acc[i][j][r] + bv + resid[gr * 512 + gc];
        }
    }
  }
}

// ---------------------------------------------------------------------------
// Tiny per-launch kernel: g[b,e], merged ln params, merged biases.
__global__ __launch_bounds__(512) void small_kernel(
    const float* __restrict__ ghsum, const float* __restrict__ g2w,
    const float* __restrict__ g2b, const float* __restrict__ lngI,
    const float* __restrict__ lnbI, const float* __restrict__ tvlg,
    const float* __restrict__ tvlb, const float* __restrict__ b1,
    const float* __restrict__ tvb1, const float* __restrict__ b2,
    const float* __restrict__ tvb2, float* __restrict__ g, float* __restrict__ lng,
    float* __restrict__ lnb, float* __restrict__ b1m, float* __restrict__ b2m) {
  __shared__ float gs[64];
  const int t = threadIdx.x;
  if (t < 64) {
    const int b = t >> 3, e = t & 7;
    float s = 0.f;
    for (int h = 0; h < 512; ++h) s += ghsum[b * 512 + h] * g2w[e * 512 + h];
    float gv = s * (1.f / 4096.f) + g2b[e];
    gs[t] = gv;
    g[t] = gv;
  }
  __syncthreads();
  if (t < 512) {
    float lg = lngI[t], lb = lnbI[t], sg = 0.f, sb = 0.f;
    for (int e = 0; e < 8; ++e) { sg += tvlg[e * 512 + t]; sb += tvlb[e * 512 + t]; }
    lng[t] = lg + 0.03f * (sg - 8.f * lg);
    lnb[t] = lb + 0.03f * (sb - 8.f * lb);
  }
  for (int i = t; i < 8 * 2048; i += 512) {
    const int b = i >> 11, f = i & 2047;
    float s = b1[f];
    for (int e = 0; e < 8; ++e) s += gs[b * 8 + e] * tvb1[e * 2048 + f];
    b1m[i] = s;
  }
  for (int i = t; i < 8 * 512; i += 512) {
    const int b = i >> 9, d = i & 511;
    float s = b2[d];
    for (int e = 0; e < 8; ++e) s += gs[b * 8 + e] * tvb2[e * 512 + d];
    b2m[i] = s;
  }
}

// ---------------------------------------------------------------------------
// Merge base + rank-8 task-vector combo into per-sample bf16 weights.
// Vectorized x4: each thread handles 4 consecutive elements, 8 samples.
__global__ __launch_bounds__(256) void merge_kernel(
    const float* __restrict__ W1, const float* __restrict__ tvW1,
    const float* __restrict__ W2, const float* __restrict__ tvW2,
    const float* __restrict__ g, bf16* __restrict__ W1m, bf16* __restrict__ W2m) {
  int idx = (blockIdx.x * 256 + threadIdx.x) * 4;
  const float* Wp;
  const float* tvp;
  bf16* outp;
  if (idx < 1048576) {
    Wp = W1; tvp = tvW1; outp = W1m;
  } else {
    idx -= 1048576;
    Wp = W2; tvp = tvW2; outp = W2m;
  }
  float4 w = *(const float4*)(Wp + idx);
  float4 tv[8];
#pragma unroll
  for (int e = 0; e < 8; ++e) tv[e] = *(const float4*)(tvp + (long)e * 1048576 + idx);
#pragma unroll
  for (int b = 0; b < 8; ++b) {
    float4 s = w;
#pragma unroll
    for (int e = 0; e < 8; ++e) {
      const float ge = g[b * 8 + e];
      s.x += ge * tv[e].x; s.y += ge * tv[e].y;
      s.z += ge * tv[e].z; s.w += ge * tv[e].w;
    }
    bf16x4 o;
    o[0] = (bf16)s.x; o[1] = (bf16)s.y; o[2] = (bf16)s.z; o[3] = (bf16)s.w;
    *(bf16x4*)(outp + (long)b * 1048576 + idx) = o;
  }
}

// ---------------------------------------------------------------------------
// In-place layernorm over D=512, one wave per row.
__global__ __launch_bounds__(256) void ln_kernel(float* __restrict__ out,
                                                 const float* __restrict__ lng,
                                                 const float* __restrict__ lnb) {
  const int wv = threadIdx.x >> 6, lane = threadIdx.x & 63;
  const long row = (long)blockIdx.x * 4 + wv;
  float* p = out + row * 512 + lane * 8;
  float4 a = *(float4*)p;
  float4 b = *(float4*)(p + 4);
  float v[8] = {a.x, a.y, a.z, a.w, b.x, b.y, b.z, b.w};
  float s1 = 0.f, s2 = 0.f;
#pragma unroll
  for (int k = 0; k < 8; ++k) { s1 += v[k]; s2 += v[k] * v[k]; }
#pragma unroll
  for (int off = 32; off > 0; off >>= 1) {
    s1 += __shfl_xor(s1, off);
    s2 += __shfl_xor(s2, off);
  }
  const float mean = s1 * (1.f / 512.f);
  const float var = s2 * (1.f / 512.f) - mean * mean;
  const float rstd = rsqrtf(var + 1e-5f);
  const int c = lane * 8;
  float o[8];
#pragma unroll
  for (int k = 0; k < 8; ++k) o[k] = (v[k] - mean) * rstd * lng[c + k] + lnb[c + k];
  *(float4*)p = make_float4(o[0], o[1], o[2], o[3]);
  *(float4*)(p + 4) = make_float4(o[4], o[5], o[6], o[7]);
}

// ---------------------------------------------------------------------------
extern "C" void kernel_launch(void* const* d_in, const int* in_sizes, int n_in,
                              void* d_out, int out_size, void* d_ws, size_t ws_size,
                              hipStream_t stream) {
  const float* x    = (const float*)d_in[0];
  const float* g1w  = (const float*)d_in[1];
  const float* g1b  = (const float*)d_in[2];
  const float* g2w  = (const float*)d_in[3];
  const float* g2b  = (const float*)d_in[4];
  const float* W1   = (const float*)d_in[5];
  const float* b1   = (const float*)d_in[6];
  const float* W2   = (const float*)d_in[7];
  const float* b2   = (const float*)d_in[8];
  const float* lngI = (const float*)d_in[9];
  const float* lnbI = (const float*)d_in[10];
  const float* tvW1 = (const float*)d_in[11];
  const float* tvb1 = (const float*)d_in[12];
  const float* tvW2 = (const float*)d_in[13];
  const float* tvb2 = (const float*)d_in[14];
  const float* tvlg = (const float*)d_in[15];
  const float* tvlb = (const float*)d_in[16];
  float* out = (float*)d_out;

  char* w = (char*)d_ws;
  bf16*  x_bf   = (bf16*)(w);                   // 33,554,432 B
  bf16*  g1w_bf = (bf16*)(w + 33554432);        //    524,288 B
  bf16*  W1m    = (bf16*)(w + 34078720);        // 16,777,216 B
  bf16*  W2m    = (bf16*)(w + 50855936);        // 16,777,216 B
  bf16*  h      = (bf16*)(w + 67633152);        // 134,217,728 B
  float* ghsum  = (float*)(w + 201850880);      //     16,384 B
  float* g      = (float*)(w + 201867264);      //        256 B
  float* b1m    = (float*)(w + 201867520);      //     65,536 B
  float* b2m    = (float*)(w + 201933056);      //     16,384 B
  float* lng    = (float*)(w + 201949440);      //      2,048 B
  float* lnb    = (float*)(w + 201951488);      //      2,048 B

  // Stage 0: fused casts + zero gate accumulator
  prep_kernel<<<8321, 256, 0, stream>>>(x, g1w, x_bf, g1w_bf, ghsum);
  // Stage 1: gate GEMM + relu column-sum   (per sample: M=4096, N=512, K=512)
  gemm_bt<0, 8><<<dim3(32, 4, 8), 256, 0, stream>>>(x_bf, g1w_bf, 0, g1b, 0,
                                                    nullptr, ghsum, nullptr);
  // Stage 2: g, merged ln params, merged biases
  small_kernel<<<1, 512, 0, stream>>>(ghsum, g2w, g2b, lngI, lnbI, tvlg, tvlb,
                                      b1, tvb1, b2, tvb2, g, lng, lnb, b1m, b2m);
  // Stage 3: per-sample weight merge -> bf16 (x4 vectorized)
  merge_kernel<<<2048, 256, 0, stream>>>(W1, tvW1, W2, tvW2, g, W1m, W2m);
  // Stage 4: h = relu(x @ W1m^T + b1m)     (per sample: M=4096, N=2048, K=512)
  gemm_bt<1, 8><<<dim3(32, 16, 8), 256, 0, stream>>>(x_bf, W1m, 1048576, b1m, 2048,
                                                     nullptr, nullptr, h);
  // Stage 5: out = h @ W2m^T + b2m + x     (per sample: M=4096, N=512, K=2048)
  gemm_bt<2, 32><<<dim3(32, 4, 8), 256, 0, stream>>>(h, W2m, 1048576, b2m, 512,
                                                     x, out, nullptr);
  // Stage 6: in-place layernorm
  ln_kernel<<<8192, 256, 0, stream>>>(out, lng, lnb);
}